// Round 6
// baseline (138.338 us; speedup 1.0000x reference)
//
#include <hip/hip_runtime.h>
#include <hip/hip_bf16.h>

// Capsule dynamic routing, factored (no u_hat), MFMA for both big einsums.
// B=64, N=2048, D=64, I=32, J=16.
//   logits b[n,i] = u[n,:].w~[i,:]   -> computed TRANSPOSED via mfma(w~, u^T):
//       C[i][n], col=n=lane&31  => softmax over i is lane-local (regs + 1 shfl)
//   t[i,d] = sum_n c[n,i] u[n,d]     -> mfma(c^T, u) with hi/lo bf16 splits
// mfma_f32_32x32x16_bf16 layouts (m74/m101-verified C; standard A/B):
//   A(MxK): row = l&31, k = (l>>5)*8 + j   (8 bf16 per lane, contiguous k)
//   B(KxN): col = l&31, k = (l>>5)*8 + j
//   C(MxN): col = l&31, row = (r&3) + 8*(r>>2) + 4*(l>>5)

#define BB 64
#define NN 2048
#define DD 64
#define II 32
#define JJ 16
#define CHROWS 128   // rows per kbig block (4 waves x 32 rows)

typedef __attribute__((ext_vector_type(8)))  short bf16x8;
typedef __attribute__((ext_vector_type(16))) float f32x16;

__device__ inline short f2bf(float f) {
    __hip_bfloat16 h = __float2bfloat16(f);
    return *reinterpret_cast<short*>(&h);
}
__device__ inline float bf2f(short s) {
    __hip_bfloat16 h = *reinterpret_cast<__hip_bfloat16*>(&s);
    return __bfloat162float(h);
}

// ---------------- kernel 1: s[b,d] = sum_n u[b,n,d] ----------------
__global__ __launch_bounds__(256) void ksum(const float* __restrict__ u,
                                            float* __restrict__ s) {
    int b = blockIdx.y;
    int cb = blockIdx.x;                    // 0..31, 64 rows each
    int d = threadIdx.x & 63;
    int g = threadIdx.x >> 6;               // 0..3
    const float* ub = u + (size_t)b * NN * DD + (size_t)(cb * 64) * DD;
    float acc = 0.f;
    #pragma unroll 4
    for (int r = g; r < 64; r += 4)
        acc += ub[(size_t)r * DD + d];      // 256B/wave coalesced
    __shared__ float red[4][64];
    red[g][d] = acc;
    __syncthreads();
    if (g == 0)
        atomicAdd(&s[b * DD + d], red[0][d] + red[1][d] + red[2][d] + red[3][d]);
}

// ---------------- small kernel: per-(b,i) o, normalize, w~ (or squash->out) ----
template <int MODE>
__global__ __launch_bounds__(512) void ksmall(const float* __restrict__ src,
                                              const float* __restrict__ W,
                                              float* __restrict__ w_out,
                                              float* __restrict__ out) {
    int b = blockIdx.x;
    int tid = threadIdx.x;                  // 512 = 32 capsules x 16 dims
    int i = tid >> 4;
    int j = tid & 15;
    const float* trow = (MODE == 0) ? (src + (size_t)b * DD)
                                    : (src + ((size_t)b * II + i) * DD);
    float o = 0.f;
    #pragma unroll 8
    for (int d = 0; d < DD; ++d)
        o += trow[d] * W[d * (II * JJ) + i * JJ + j];
    if (MODE == 0) o *= (1.0f / 32.0f);

    float ss = o * o;
    #pragma unroll
    for (int off = 8; off >= 1; off >>= 1)
        ss += __shfl_xor(ss, off, 16);

    if (MODE == 2) {
        float s2 = ss + 1e-7f;                       // K.epsilon
        float scale = sqrtf(s2) / (0.5f + s2);       // squash
        out[((size_t)b * II + i) * JJ + j] = scale * o;
        return;
    }

    float norm = sqrtf(fmaxf(ss, 1e-12f));           // tf l2_normalize
    float ov = o / norm;
    __shared__ float osh[II][JJ];
    osh[i][j] = ov;
    __syncthreads();
    #pragma unroll
    for (int k = 0; k < 4; ++k) {
        int d = j + 16 * k;
        float acc = 0.f;
        #pragma unroll
        for (int jj = 0; jj < 16; ++jj)
            acc += W[d * (II * JJ) + i * JJ + jj] * osh[i][jj];
        w_out[((size_t)b * II + i) * DD + d] = acc;
    }
}

// ---------------- big kernel: one routing pass (MFMA) ----------------
__global__ __launch_bounds__(256) void kbig(const float* __restrict__ u,
                                            const float* __restrict__ w,
                                            float* __restrict__ t) {
    int b = blockIdx.y;
    int chunk = blockIdx.x;                 // 0..15, CHROWS rows each
    int tid = threadIdx.x;
    int wv = tid >> 6;                      // wave 0..3, owns 32 rows
    int l  = tid & 63;
    int h  = l >> 5;                        // half
    int ln = l & 31;

    __shared__ float clds[CHROWS][II + 1];  // c[n_local][i], pad 33 -> conflict-free
    __shared__ float tlds[II][DD + 1];      // t[i][d] block-local reduce, pad 65

    float* tldsf = &tlds[0][0];
    for (int k = tid; k < II * (DD + 1); k += 256) tldsf[k] = 0.f;

    // ---- logits: C[i][n] = sum_d w~[i][d] * u[n][d], one 32x32 tile/wave ----
    const float* wbase = w + (size_t)b * II * DD;
    int nrow = chunk * CHROWS + wv * 32 + ln;       // this lane's n (as B col)
    const float* urow = u + ((size_t)b * NN + nrow) * DD;
    const float* wrow = wbase + (size_t)ln * DD;    // this lane's i (as A row)

    f32x16 S;
    #pragma unroll
    for (int r = 0; r < 16; ++r) S[r] = 0.f;

    #pragma unroll
    for (int kt = 0; kt < 4; ++kt) {                // k-step over d
        int dofs = kt * 16 + h * 8;
        float4 a0 = *reinterpret_cast<const float4*>(wrow + dofs);
        float4 a1 = *reinterpret_cast<const float4*>(wrow + dofs + 4);
        float4 b0 = *reinterpret_cast<const float4*>(urow + dofs);
        float4 b1 = *reinterpret_cast<const float4*>(urow + dofs + 4);
        bf16x8 A, Bv;
        A[0]=f2bf(a0.x); A[1]=f2bf(a0.y); A[2]=f2bf(a0.z); A[3]=f2bf(a0.w);
        A[4]=f2bf(a1.x); A[5]=f2bf(a1.y); A[6]=f2bf(a1.z); A[7]=f2bf(a1.w);
        Bv[0]=f2bf(b0.x); Bv[1]=f2bf(b0.y); Bv[2]=f2bf(b0.z); Bv[3]=f2bf(b0.w);
        Bv[4]=f2bf(b1.x); Bv[5]=f2bf(b1.y); Bv[6]=f2bf(b1.z); Bv[7]=f2bf(b1.w);
        S = __builtin_amdgcn_mfma_f32_32x32x16_bf16(A, Bv, S, 0, 0, 0);
    }

    // ---- softmax over i: regs hold 16 i's, partner half has the other 16 ----
    float m = S[0];
    #pragma unroll
    for (int r = 1; r < 16; ++r) m = fmaxf(m, S[r]);
    m = fmaxf(m, __shfl_xor(m, 32));
    float sum = 0.f;
    float e[16];
    #pragma unroll
    for (int r = 0; r < 16; ++r) { e[r] = __expf(S[r] - m); sum += e[r]; }
    sum += __shfl_xor(sum, 32);
    float inv = 1.f / sum;
    #pragma unroll
    for (int r = 0; r < 16; ++r) {
        int irow = (r & 3) + 8 * (r >> 2) + 4 * h;
        clds[wv * 32 + ln][irow] = e[r] * inv;       // c[n][i]
    }
    __syncthreads();   // clds ready; tlds zero-init visible

    // ---- t-GEMM: C[i][d] += sum_n c[n][i]*u[n][d]; A=c^T hi/lo, B=u hi/lo ----
    f32x16 G0, G1;
    #pragma unroll
    for (int r = 0; r < 16; ++r) { G0[r] = 0.f; G1[r] = 0.f; }

    bf16x8 Ah[2], Al[2];
    #pragma unroll
    for (int t2 = 0; t2 < 2; ++t2) {
        int nb = wv * 32 + t2 * 16 + h * 8;         // k-run base (local n)
        #pragma unroll
        for (int jj = 0; jj < 8; ++jj) {
            float cv = clds[nb + jj][ln];           // c[n][i=ln]
            short hi = f2bf(cv);
            Ah[t2][jj] = hi;
            Al[t2][jj] = f2bf(cv - bf2f(hi));
        }
    }

    #pragma unroll
    for (int t2 = 0; t2 < 2; ++t2) {
        int ng = chunk * CHROWS + wv * 32 + t2 * 16 + h * 8;  // global n base
        #pragma unroll
        for (int Nt = 0; Nt < 2; ++Nt) {
            const float* ucol = u + ((size_t)b * NN + ng) * DD + Nt * 32 + ln;
            bf16x8 Bh, Bl;
            #pragma unroll
            for (int jj = 0; jj < 8; ++jj) {
                float uv = ucol[(size_t)jj * DD];   // 128B-line exact per jj
                short hi = f2bf(uv);
                Bh[jj] = hi;
                Bl[jj] = f2bf(uv - bf2f(hi));
            }
            if (Nt == 0) {
                G0 = __builtin_amdgcn_mfma_f32_32x32x16_bf16(Ah[t2], Bh, G0, 0, 0, 0);
                G0 = __builtin_amdgcn_mfma_f32_32x32x16_bf16(Al[t2], Bh, G0, 0, 0, 0);
                G0 = __builtin_amdgcn_mfma_f32_32x32x16_bf16(Ah[t2], Bl, G0, 0, 0, 0);
            } else {
                G1 = __builtin_amdgcn_mfma_f32_32x32x16_bf16(Ah[t2], Bh, G1, 0, 0, 0);
                G1 = __builtin_amdgcn_mfma_f32_32x32x16_bf16(Al[t2], Bh, G1, 0, 0, 0);
                G1 = __builtin_amdgcn_mfma_f32_32x32x16_bf16(Ah[t2], Bl, G1, 0, 0, 0);
            }
        }
    }

    // ---- reduce: LDS atomic (2-way alias max), then one flush per block ----
    #pragma unroll
    for (int r = 0; r < 16; ++r) {
        int irow = (r & 3) + 8 * (r >> 2) + 4 * h;
        atomicAdd(&tlds[irow][ln],      G0[r]);
        atomicAdd(&tlds[irow][32 + ln], G1[r]);
    }
    __syncthreads();
    for (int k = tid; k < II * DD; k += 256) {
        atomicAdd(&t[(size_t)b * II * DD + k], tlds[k >> 6][k & 63]);
    }
}

extern "C" void kernel_launch(void* const* d_in, const int* in_sizes, int n_in,
                              void* d_out, int out_size, void* d_ws, size_t ws_size,
                              hipStream_t stream) {
    const float* u = (const float*)d_in[0];     // (64, 2048, 64)
    const float* W = (const float*)d_in[1];     // (1, 64, 512)
    float* out = (float*)d_out;                 // (64, 32, 16)
    float* ws = (float*)d_ws;

    float* s    = ws;                           // 4096 floats
    float* t1   = ws + 4096;                    // 131072 floats
    float* t2   = ws + 4096 + 131072;           // 131072 floats
    float* wtil = ws + 4096 + 2 * 131072;       // 131072 floats (w~)

    // zero the atomically-accumulated buffers (harness does not re-poison)
    hipMemsetAsync(ws, 0, (4096 + 2 * 131072) * sizeof(float), stream);

    ksum<<<dim3(32, BB), 256, 0, stream>>>(u, s);
    ksmall<0><<<BB, 512, 0, stream>>>(s, W, wtil, nullptr);     // iter0: uniform c
    kbig<<<dim3(NN / CHROWS, BB), 256, 0, stream>>>(u, wtil, t1);
    ksmall<1><<<BB, 512, 0, stream>>>(t1, W, wtil, nullptr);
    kbig<<<dim3(NN / CHROWS, BB), 256, 0, stream>>>(u, wtil, t2);
    ksmall<2><<<BB, 512, 0, stream>>>(t2, W, nullptr, out);     // squash -> out
}